// Round 3
// baseline (353.100 us; speedup 1.0000x reference)
//
#include <hip/hip_runtime.h>
#include <stdint.h>

#define N_ANCH 262144
#define NUM_CLASSES 80
#define DET_DIM 84
#define TOP_K 1000
#define MAX_BOXES 300
#define NMS_THR 0.4f

// ---- workspace layout (bytes) ----
#define OFF_KEYS   0u
#define OFF_HIST1  (N_ANCH * 4u)             // 4096 u32
#define OFF_HIST2  (OFF_HIST1 + 16384u)      // 4096 u32
#define OFF_STATE  (OFF_HIST2 + 16384u)      // 16 u32: 0:d1 1:k1 2:pre24 3:cnt
#define OFF_LIST   (OFF_STATE + 64u)         // 4096 u32 candidate indices
#define OFF_TOPK   (OFF_LIST + 16384u)       // 1024 u32
#define OFF_BOXK   (OFF_TOPK + 4096u)        // 1024 float4
#define OFF_MASK   (OFF_BOXK + 16384u)       // 1024 rows x 16 u64 = 128 KB

// zero hist1 + hist2 + state contiguously
#define ZERO_WORDS ((16384u + 16384u + 64u) / 4u)   // 8208

__global__ __launch_bounds__(1024) void k_init(uint32_t* __restrict__ z) {
    uint32_t tid = blockIdx.x * 1024u + threadIdx.x;
    if (tid < ZERO_WORDS) z[tid] = 0u;
}

// scores = max over 80 classes; key = float bits (scores >= 0 => monotonic)
__global__ __launch_bounds__(256) void k_scores(const float* __restrict__ cls,
                                                uint32_t* __restrict__ keys,
                                                uint32_t* __restrict__ ghist1) {
    __shared__ uint32_t h[4096];
    for (int i = threadIdx.x; i < 4096; i += 256) h[i] = 0u;
    __syncthreads();
    int a = blockIdx.x * 256 + threadIdx.x;   // grid sized to exactly N_ANCH
    const float4* q = (const float4*)(cls + (size_t)a * NUM_CLASSES);
    float m = -1.0f;
#pragma unroll
    for (int t = 0; t < 20; ++t) {
        float4 v = q[t];
        m = fmaxf(m, fmaxf(fmaxf(v.x, v.y), fmaxf(v.z, v.w)));
    }
    uint32_t key = __float_as_uint(m);
    keys[a] = key;
    atomicAdd(&h[key >> 20], 1u);
    __syncthreads();
    for (int i = threadIdx.x; i < 4096; i += 256) {
        uint32_t v = h[i];
        if (v) atomicAdd(&ghist1[i], v);
    }
}

// wave(64-lane) suffix-scan of a histogram: find bin d with S(d+1) < k <= S(d)
// writes d -> out[0], k - S(d+1) -> out[1]  (exactly one lane writes)
__device__ __forceinline__ void wave_scan_hist(const uint32_t* __restrict__ hist,
                                               int nbins, uint32_t k,
                                               uint32_t* __restrict__ out, int lane) {
    int per = nbins >> 6;
    int base = lane * per;
    uint32_t partial = 0;
    for (int b = 0; b < per; ++b) partial += hist[base + b];
    uint32_t si = partial;
#pragma unroll
    for (int off = 1; off < 64; off <<= 1) {
        uint32_t v = __shfl_down(si, off);
        if (lane + off < 64) si += v;
    }
    uint32_t se = si - partial;
    if (se < k && k <= si) {
        uint32_t running = se;
        for (int b = base + per - 1; b >= base; --b) {
            uint32_t hv = hist[b];
            running += hv;
            if (running >= k) {
                out[0] = (uint32_t)b;
                out[1] = k - (running - hv);
                break;
            }
        }
    }
}

// pass 2: every block redoes the (cheap) scan of hist1, then histograms bits[19:8]
__global__ __launch_bounds__(256) void k_pass2(const uint32_t* __restrict__ keys,
                                               const uint32_t* __restrict__ ghist1,
                                               uint32_t* __restrict__ ghist2,
                                               uint32_t* __restrict__ state) {
    __shared__ uint32_t sd[2];
    __shared__ uint32_t h[4096];
    if (threadIdx.x < 64) wave_scan_hist(ghist1, 4096, TOP_K, sd, threadIdx.x);
    for (int i = threadIdx.x; i < 4096; i += 256) h[i] = 0u;
    __syncthreads();
    uint32_t d1 = sd[0], k1 = sd[1];
    if (threadIdx.x == 0 && blockIdx.x == 0) { state[0] = d1; state[1] = k1; }
    int stride = gridDim.x * 256;
    for (int a = blockIdx.x * 256 + threadIdx.x; a < N_ANCH; a += stride) {
        uint32_t key = keys[a];
        if ((key >> 20) == d1) atomicAdd(&h[(key >> 8) & 0xFFFu], 1u);
    }
    __syncthreads();
    for (int i = threadIdx.x; i < 4096; i += 256) {
        uint32_t v = h[i];
        if (v) atomicAdd(&ghist2[i], v);
    }
}

// pass 3: scan hist2 -> pre24; compact ALL indices with (key>>8) >= pre24.
// Exact: any excluded key is strictly smaller in its top 24 bits than every candidate.
__global__ __launch_bounds__(256) void k_pass3c(const uint32_t* __restrict__ keys,
                                                const uint32_t* __restrict__ ghist2,
                                                uint32_t* __restrict__ state,
                                                uint32_t* __restrict__ list) {
    __shared__ uint32_t sd[2];
    if (threadIdx.x < 64) {
        uint32_t k1 = state[1];
        wave_scan_hist(ghist2, 4096, k1, sd, threadIdx.x);
    }
    __syncthreads();
    uint32_t pre24 = (state[0] << 12) | sd[0];
    if (threadIdx.x == 0 && blockIdx.x == 0) state[2] = pre24;
    int stride = gridDim.x * 256;
    for (int a = blockIdx.x * 256 + threadIdx.x; a < N_ANCH; a += stride) {
        uint32_t key = keys[a];
        if ((key >> 8) >= pre24) {
            uint32_t p = atomicAdd(&state[3], 1u);
            if (p < 4096u) list[p] = (uint32_t)a;
        }
    }
}

// single block: bitonic-sort candidates by (key desc, idx asc), emit topk + gather boxes
__global__ __launch_bounds__(1024) void k_sort(const uint32_t* __restrict__ keys,
                                               const uint32_t* __restrict__ state,
                                               const uint32_t* __restrict__ list,
                                               uint32_t* __restrict__ topk,
                                               const float4* __restrict__ boxes,
                                               float4* __restrict__ boxk) {
    __shared__ unsigned long long A[4096];
    int t = threadIdx.x;
    uint32_t cnt = state[3];
    if (cnt > 4096u) cnt = 4096u;          // expected ~1320
    unsigned n2 = 1024; while (n2 < cnt) n2 <<= 1;   // cnt >= 1000 always
    for (unsigned i = (unsigned)t; i < n2; i += 1024) {
        unsigned long long wv = ~0ull;
        if (i < cnt) {
            uint32_t idx = list[i];
            wv = ((unsigned long long)(~keys[idx]) << 32) | (unsigned long long)idx;
        }
        A[i] = wv;
    }
    __syncthreads();
    for (unsigned k = 2; k <= n2; k <<= 1) {
        for (unsigned j = k >> 1; j > 0; j >>= 1) {
            for (unsigned i = (unsigned)t; i < n2; i += 1024) {
                unsigned ixj = i ^ j;
                if (ixj > i) {
                    unsigned long long a = A[i], b = A[ixj];
                    bool up = ((i & k) == 0);
                    if (up ? (a > b) : (a < b)) { A[i] = b; A[ixj] = a; }
                }
            }
            __syncthreads();
        }
    }
    if (t < TOP_K) {
        uint32_t idx = (uint32_t)(A[t] & 0xFFFFFFFFull);
        topk[t] = idx;
        boxk[t] = boxes[idx];
    }
}

// mask[i][w] bit b: box j=64w+b suppressed by box i (iou>thr && j>i); rows >=1000 zeroed.
__global__ __launch_bounds__(256) void k_mask(const float4* __restrict__ boxk,
                                              unsigned long long* __restrict__ mask) {
    int lane = threadIdx.x & 63;
    int wave = threadIdx.x >> 6;
    for (int r = 0; r < 4; ++r) {
        int i = blockIdx.x * 4 + r;
        if (i >= 1000) {
            if (threadIdx.x < 16) mask[(size_t)i * 16 + threadIdx.x] = 0ull;
            continue;
        }
        float4 bi = boxk[i];
        float areai = __fmul_rn(__fsub_rn(bi.z, bi.x), __fsub_rn(bi.w, bi.y));
#pragma unroll
        for (int rr = 0; rr < 4; ++rr) {
            int j = rr * 256 + threadIdx.x;
            bool bit = false;
            if (j < 1000 && j > i) {
                float4 bj = boxk[j];
                float areaj = __fmul_rn(__fsub_rn(bj.z, bj.x), __fsub_rn(bj.w, bj.y));
                float ix1 = fmaxf(bi.x, bj.x);
                float iy1 = fmaxf(bi.y, bj.y);
                float ix2 = fminf(bi.z, bj.z);
                float iy2 = fminf(bi.w, bj.w);
                float iw = fmaxf(__fsub_rn(ix2, ix1), 0.0f);
                float ih = fmaxf(__fsub_rn(iy2, iy1), 0.0f);
                float inter = __fmul_rn(iw, ih);
                float uni = __fsub_rn(__fadd_rn(areai, areaj), inter);
                float den = fmaxf(uni, 1e-8f);
                float iou = inter / den;   // IEEE RN divide, matches jnp
                bit = iou > NMS_THR;
            }
            unsigned long long bal = __ballot(bit);
            if (lane == 0) mask[(size_t)i * 16 + (rr * 4 + wave)] = bal;
        }
    }
}

// fused greedy NMS + output gather.
// Wave 0 runs the serial scan with a VALU-only dependency chain:
//   - per chunk, rows' in-chunk words go to LDS once; all 64 lanes redundantly
//     run the 64-step resolution on broadcast LDS reads (reads independent of
//     the supp chain -> compiler batches them; chain is pure VALU).
//   - global 1000-bit suppression mask lives distributed: lane l<16 holds word l;
//     after each chunk, kept boxes' 128B mask rows are coalesced-ORed in.
__global__ __launch_bounds__(256) void k_nms_out(const unsigned long long* __restrict__ mask,
                                                 const uint32_t* __restrict__ topk,
                                                 const float* __restrict__ det,
                                                 float* __restrict__ out) {
    __shared__ unsigned long long rowS[64];
    __shared__ uint32_t keptList[384];
    __shared__ uint32_t selS[MAX_BOXES];
    int lane = threadIdx.x & 63;
    int wave = threadIdx.x >> 6;
    if (wave == 0) {
        unsigned long long suppAll = 0ull;   // lane l<16: word l of global supp mask
        uint32_t keptCount = 0;
        for (int c = 0; c < 16 && keptCount < MAX_BOXES; ++c) {
            // supp-so-far for this chunk: broadcast word c from lane c
            unsigned long long supp = __shfl(suppAll, c);
            // stage this chunk's 64 in-chunk row words in LDS
            rowS[lane] = mask[(size_t)(c * 64 + lane) * 16 + c];
            asm volatile("s_waitcnt lgkmcnt(0)" ::: "memory");
            // serial greedy resolution, branchless, redundant on all lanes
            unsigned long long kept = 0ull;
#pragma unroll
            for (int i = 0; i < 64; ++i) {
                unsigned long long ri = rowS[i];                       // LDS broadcast
                unsigned long long actm = ((supp >> i) & 1ull) - 1ull; // ~0 if active
                supp |= ri & actm;
                kept |= (1ull << i) & actm;
            }
            if (c == 15) kept &= (1ull << 40) - 1ull;   // only 1000 boxes
            uint32_t cnt = (uint32_t)__popcll(kept);
            if ((kept >> lane) & 1ull) {
                uint32_t pos = keptCount + (uint32_t)__popcll(kept & ((1ull << lane) - 1ull));
                if (pos < 384u) keptList[pos] = (uint32_t)(c * 64 + lane);
            }
            // fold kept boxes' full rows into the distributed global supp mask
            unsigned long long kk = kept;
            while (kk) {
                int j = __builtin_ctzll(kk);
                kk &= kk - 1ull;
                if (lane < 16)
                    suppAll |= mask[(size_t)(c * 64 + j) * 16 + lane]; // 128B coalesced
            }
            keptCount += cnt;
        }
        if (keptCount > MAX_BOXES) keptCount = MAX_BOXES;
        asm volatile("s_waitcnt lgkmcnt(0)" ::: "memory");
        for (uint32_t m = (uint32_t)lane; m < MAX_BOXES; m += 64u)
            selS[m] = (m < keptCount) ? topk[keptList[m]] : 0xFFFFFFFFu;
    }
    __syncthreads();
    // gather 300 x 84 output rows (4 waves x 75 rows)
    for (int m = wave; m < MAX_BOXES; m += 4) {
        uint32_t s = selS[m];
        const float* src = det + (size_t)s * DET_DIM;
        for (int e = lane; e < DET_DIM; e += 64)
            out[m * DET_DIM + e] = (s == 0xFFFFFFFFu) ? 0.0f : src[e];
    }
}

extern "C" void kernel_launch(void* const* d_in, const int* in_sizes, int n_in,
                              void* d_out, int out_size, void* d_ws, size_t ws_size,
                              hipStream_t stream) {
    const float* boxes = (const float*)d_in[0];
    const float* cls   = (const float*)d_in[1];
    const float* det   = (const float*)d_in[2];
    float* out = (float*)d_out;
    char* ws = (char*)d_ws;

    uint32_t* keys = (uint32_t*)(ws + OFF_KEYS);
    uint32_t* h1   = (uint32_t*)(ws + OFF_HIST1);
    uint32_t* h2   = (uint32_t*)(ws + OFF_HIST2);
    uint32_t* st   = (uint32_t*)(ws + OFF_STATE);
    uint32_t* list = (uint32_t*)(ws + OFF_LIST);
    uint32_t* topk = (uint32_t*)(ws + OFF_TOPK);
    float4*   boxk = (float4*)(ws + OFF_BOXK);
    unsigned long long* mask = (unsigned long long*)(ws + OFF_MASK);

    k_init<<<dim3((ZERO_WORDS + 1023) / 1024), dim3(1024), 0, stream>>>(h1);
    k_scores<<<dim3(N_ANCH / 256), dim3(256), 0, stream>>>(cls, keys, h1);
    k_pass2<<<dim3(256), dim3(256), 0, stream>>>(keys, h1, h2, st);
    k_pass3c<<<dim3(256), dim3(256), 0, stream>>>(keys, h2, st, list);
    k_sort<<<dim3(1), dim3(1024), 0, stream>>>(keys, st, list, topk,
                                               (const float4*)boxes, boxk);
    k_mask<<<dim3(256), dim3(256), 0, stream>>>(boxk, mask);
    k_nms_out<<<dim3(1), dim3(256), 0, stream>>>(mask, topk, det, out);
}

// Round 4
// 255.108 us; speedup vs baseline: 1.3841x; 1.3841x over previous
//
#include <hip/hip_runtime.h>
#include <stdint.h>

#define N_ANCH 262144
#define NUM_CLASSES 80
#define DET_DIM 84
#define TOP_K 1000
#define MAX_BOXES 300
#define NMS_THR 0.4f

// ---- workspace layout (bytes) ----
#define OFF_KEYS   0u
#define OFF_HIST1  (N_ANCH * 4u)             // 4096 u32
#define OFF_HIST2  (OFF_HIST1 + 16384u)      // 4096 u32
#define OFF_STATE  (OFF_HIST2 + 16384u)      // 16 u32: 0:d1 1:k1 2:pre24 3:cnt
#define OFF_LIST   (OFF_STATE + 64u)         // 4096 u32 candidate indices
#define OFF_TOPK   (OFF_LIST + 16384u)       // 1024 u32
#define OFF_BOXK   (OFF_TOPK + 4096u)        // 1024 float4
#define OFF_MASK   (OFF_BOXK + 16384u)       // 1024 rows x 16 u64 = 128 KB
#define OFF_SEL    (OFF_MASK + 131072u)      // 304 u32

// zero hist1 + hist2 + state contiguously
#define ZERO_WORDS ((16384u + 16384u + 64u) / 4u)   // 8208

__global__ __launch_bounds__(1024) void k_init(uint32_t* __restrict__ z) {
    uint32_t tid = blockIdx.x * 1024u + threadIdx.x;
    if (tid < ZERO_WORDS) z[tid] = 0u;
}

// scores = max over 80 classes; key = float bits (scores >= 0 => monotonic)
__global__ __launch_bounds__(256) void k_scores(const float* __restrict__ cls,
                                                uint32_t* __restrict__ keys,
                                                uint32_t* __restrict__ ghist1) {
    __shared__ uint32_t h[4096];
    for (int i = threadIdx.x; i < 4096; i += 256) h[i] = 0u;
    __syncthreads();
    int a = blockIdx.x * 256 + threadIdx.x;   // grid sized to exactly N_ANCH
    const float4* q = (const float4*)(cls + (size_t)a * NUM_CLASSES);
    float m = -1.0f;
#pragma unroll
    for (int t = 0; t < 20; ++t) {
        float4 v = q[t];
        m = fmaxf(m, fmaxf(fmaxf(v.x, v.y), fmaxf(v.z, v.w)));
    }
    uint32_t key = __float_as_uint(m);
    keys[a] = key;
    atomicAdd(&h[key >> 20], 1u);
    __syncthreads();
    for (int i = threadIdx.x; i < 4096; i += 256) {
        uint32_t v = h[i];
        if (v) atomicAdd(&ghist1[i], v);
    }
}

// wave(64-lane) suffix-scan of a histogram: find bin d with S(d+1) < k <= S(d)
// writes d -> out[0], k - S(d+1) -> out[1]  (exactly one lane writes)
__device__ __forceinline__ void wave_scan_hist(const uint32_t* __restrict__ hist,
                                               int nbins, uint32_t k,
                                               uint32_t* __restrict__ out, int lane) {
    int per = nbins >> 6;
    int base = lane * per;
    uint32_t partial = 0;
    for (int b = 0; b < per; ++b) partial += hist[base + b];
    uint32_t si = partial;
#pragma unroll
    for (int off = 1; off < 64; off <<= 1) {
        uint32_t v = __shfl_down(si, off);
        if (lane + off < 64) si += v;
    }
    uint32_t se = si - partial;
    if (se < k && k <= si) {
        uint32_t running = se;
        for (int b = base + per - 1; b >= base; --b) {
            uint32_t hv = hist[b];
            running += hv;
            if (running >= k) {
                out[0] = (uint32_t)b;
                out[1] = k - (running - hv);
                break;
            }
        }
    }
}

// pass 2: every block redoes the (cheap) scan of hist1, then histograms bits[19:8]
__global__ __launch_bounds__(256) void k_pass2(const uint32_t* __restrict__ keys,
                                               const uint32_t* __restrict__ ghist1,
                                               uint32_t* __restrict__ ghist2,
                                               uint32_t* __restrict__ state) {
    __shared__ uint32_t sd[2];
    __shared__ uint32_t h[4096];
    if (threadIdx.x < 64) wave_scan_hist(ghist1, 4096, TOP_K, sd, threadIdx.x);
    for (int i = threadIdx.x; i < 4096; i += 256) h[i] = 0u;
    __syncthreads();
    uint32_t d1 = sd[0], k1 = sd[1];
    if (threadIdx.x == 0 && blockIdx.x == 0) { state[0] = d1; state[1] = k1; }
    int stride = gridDim.x * 256;
    for (int a = blockIdx.x * 256 + threadIdx.x; a < N_ANCH; a += stride) {
        uint32_t key = keys[a];
        if ((key >> 20) == d1) atomicAdd(&h[(key >> 8) & 0xFFFu], 1u);
    }
    __syncthreads();
    for (int i = threadIdx.x; i < 4096; i += 256) {
        uint32_t v = h[i];
        if (v) atomicAdd(&ghist2[i], v);
    }
}

// pass 3: scan hist2 -> pre24; compact ALL indices with (key>>8) >= pre24.
// Exact: any excluded key is strictly smaller in its top 24 bits than every candidate.
__global__ __launch_bounds__(256) void k_pass3c(const uint32_t* __restrict__ keys,
                                                const uint32_t* __restrict__ ghist2,
                                                uint32_t* __restrict__ state,
                                                uint32_t* __restrict__ list) {
    __shared__ uint32_t sd[2];
    if (threadIdx.x < 64) {
        uint32_t k1 = state[1];
        wave_scan_hist(ghist2, 4096, k1, sd, threadIdx.x);
    }
    __syncthreads();
    uint32_t pre24 = (state[0] << 12) | sd[0];
    if (threadIdx.x == 0 && blockIdx.x == 0) state[2] = pre24;
    int stride = gridDim.x * 256;
    for (int a = blockIdx.x * 256 + threadIdx.x; a < N_ANCH; a += stride) {
        uint32_t key = keys[a];
        if ((key >> 8) >= pre24) {
            uint32_t p = atomicAdd(&state[3], 1u);
            if (p < 4096u) list[p] = (uint32_t)a;
        }
    }
}

// single block: bitonic-sort candidates by (key desc, idx asc), emit topk + gather boxes
__global__ __launch_bounds__(1024) void k_sort(const uint32_t* __restrict__ keys,
                                               const uint32_t* __restrict__ state,
                                               const uint32_t* __restrict__ list,
                                               uint32_t* __restrict__ topk,
                                               const float4* __restrict__ boxes,
                                               float4* __restrict__ boxk) {
    __shared__ unsigned long long A[4096];
    int t = threadIdx.x;
    uint32_t cnt = state[3];
    if (cnt > 4096u) cnt = 4096u;          // expected ~1320
    unsigned n2 = 1024; while (n2 < cnt) n2 <<= 1;   // cnt >= 1000 always
    for (unsigned i = (unsigned)t; i < n2; i += 1024) {
        unsigned long long wv = ~0ull;
        if (i < cnt) {
            uint32_t idx = list[i];
            wv = ((unsigned long long)(~keys[idx]) << 32) | (unsigned long long)idx;
        }
        A[i] = wv;
    }
    __syncthreads();
    for (unsigned k = 2; k <= n2; k <<= 1) {
        for (unsigned j = k >> 1; j > 0; j >>= 1) {
            for (unsigned i = (unsigned)t; i < n2; i += 1024) {
                unsigned ixj = i ^ j;
                if (ixj > i) {
                    unsigned long long a = A[i], b = A[ixj];
                    bool up = ((i & k) == 0);
                    if (up ? (a > b) : (a < b)) { A[i] = b; A[ixj] = a; }
                }
            }
            __syncthreads();
        }
    }
    if (t < TOP_K) {
        uint32_t idx = (uint32_t)(A[t] & 0xFFFFFFFFull);
        topk[t] = idx;
        boxk[t] = boxes[idx];
    }
}

// mask[i][w] bit b: box j=64w+b suppressed by box i (iou>thr && j>i); rows >=1000 zeroed.
__global__ __launch_bounds__(256) void k_mask(const float4* __restrict__ boxk,
                                              unsigned long long* __restrict__ mask) {
    int lane = threadIdx.x & 63;
    int wave = threadIdx.x >> 6;
    for (int r = 0; r < 4; ++r) {
        int i = blockIdx.x * 4 + r;
        if (i >= 1000) {
            if (threadIdx.x < 16) mask[(size_t)i * 16 + threadIdx.x] = 0ull;
            continue;
        }
        float4 bi = boxk[i];
        float areai = __fmul_rn(__fsub_rn(bi.z, bi.x), __fsub_rn(bi.w, bi.y));
#pragma unroll
        for (int rr = 0; rr < 4; ++rr) {
            int j = rr * 256 + threadIdx.x;
            bool bit = false;
            if (j < 1000 && j > i) {
                float4 bj = boxk[j];
                float areaj = __fmul_rn(__fsub_rn(bj.z, bj.x), __fsub_rn(bj.w, bj.y));
                float ix1 = fmaxf(bi.x, bj.x);
                float iy1 = fmaxf(bi.y, bj.y);
                float ix2 = fminf(bi.z, bj.z);
                float iy2 = fminf(bi.w, bj.w);
                float iw = fmaxf(__fsub_rn(ix2, ix1), 0.0f);
                float ih = fmaxf(__fsub_rn(iy2, iy1), 0.0f);
                float inter = __fmul_rn(iw, ih);
                float uni = __fsub_rn(__fadd_rn(areai, areaj), inter);
                float den = fmaxf(uni, 1e-8f);
                float iou = inter / den;   // IEEE RN divide, matches jnp
                bit = iou > NMS_THR;
            }
            unsigned long long bal = __ballot(bit);
            if (lane == 0) mask[(size_t)i * 16 + (rr * 4 + wave)] = bal;
        }
    }
}

// Greedy NMS, single block of 4 waves:
//  - waves 1..3 double-buffer-stage the NEXT chunk's full 64x16 u64 mask rows
//    into LDS (8 KB, coalesced 16B loads; no data-dependent global loads).
//  - wave 0: (a) resolves the 64-step greedy chain from LDS-broadcast reads
//    pre-batched into registers (pure-VALU dep chain); (b) folds kept rows into
//    the lane-distributed 1000-bit global suppression mask fully in parallel
//    (4 groups x 16 words, fixed-trip predicated LDS reads + 2 shfl_xor).
__global__ __launch_bounds__(256) void k_nms(const unsigned long long* __restrict__ mask,
                                             const uint32_t* __restrict__ topk,
                                             uint32_t* __restrict__ sel) {
    __shared__ unsigned long long rowBlk[2][64 * 16];
    __shared__ uint32_t keptList[384];
    __shared__ uint32_t doneS;
    int t = threadIdx.x;
    int lane = t & 63;
    int wave = t >> 6;

    // stage chunk 0 into buffer 0 (all 256 threads)
    {
        const ulonglong2* src = (const ulonglong2*)mask;      // chunk 0 = first 1024 u64
        ulonglong2* dst = (ulonglong2*)rowBlk[0];
        for (int i = t; i < 512; i += 256) dst[i] = src[i];
    }
    if (t == 0) doneS = 0u;
    __syncthreads();

    unsigned long long suppAll = 0ull;   // lane l<16 holds word l of global supp mask
    uint32_t keptCount = 0;

    for (int c = 0; c < 16; ++c) {
        if (wave != 0) {
            int cn = c + 1;
            if (cn < 16) {
                const ulonglong2* src = (const ulonglong2*)(mask + (size_t)cn * 1024);
                ulonglong2* dst = (ulonglong2*)rowBlk[cn & 1];
                for (int i = t - 64; i < 512; i += 192) dst[i] = src[i];
            }
        } else {
            const unsigned long long* blk = rowBlk[c & 1];
            unsigned long long supp = __shfl(suppAll, c);
            unsigned long long kept = 0ull;
            // serial greedy resolution: 4 batches of 16 rows; LDS broadcast reads
            // batched into registers ahead of the pure-VALU dependency chain
#pragma unroll
            for (int b = 0; b < 4; ++b) {
                unsigned long long r[16];
#pragma unroll
                for (int q = 0; q < 16; ++q) r[q] = blk[(b * 16 + q) * 16 + c];
#pragma unroll
                for (int q = 0; q < 16; ++q) {
                    int i = b * 16 + q;
                    unsigned long long actm = ((supp >> i) & 1ull) - 1ull; // ~0 if active
                    supp |= r[q] & actm;
                    kept |= (1ull << i) & actm;
                }
            }
            if (c == 15) kept &= (1ull << 40) - 1ull;   // only 1000 boxes total
            uint32_t cnt = (uint32_t)__popcll(kept);
            if ((kept >> lane) & 1ull) {
                uint32_t pos = keptCount + (uint32_t)__popcll(kept & ((1ull << lane) - 1ull));
                if (pos < 384u) keptList[pos] = (uint32_t)(c * 64 + lane);
            }
            // parallel fold of kept rows into distributed global supp mask
            int g = lane >> 4, w = lane & 15;
            unsigned long long acc = 0ull;
#pragma unroll
            for (int s = 0; s < 16; ++s) {
                int j = g * 16 + s;
                unsigned long long mj = 0ull - ((kept >> j) & 1ull);  // ~0 if kept
                acc |= blk[j * 16 + w] & mj;
            }
            acc |= __shfl_xor(acc, 16);
            acc |= __shfl_xor(acc, 32);
            suppAll |= acc;            // meaningful on lanes<16 only
            keptCount += cnt;
            if (lane == 0) doneS = (keptCount >= MAX_BOXES) ? 1u : 0u;
        }
        __syncthreads();
        if (doneS) break;
    }

    if (wave == 0) {
        uint32_t kc = keptCount > MAX_BOXES ? MAX_BOXES : keptCount;
        for (uint32_t m = (uint32_t)lane; m < MAX_BOXES; m += 64u)
            sel[m] = (m < kc) ? topk[keptList[m]] : 0xFFFFFFFFu;
    }
}

// wide parallel output gather: one element per thread
__global__ __launch_bounds__(256) void k_out(const uint32_t* __restrict__ sel,
                                             const float* __restrict__ det,
                                             float* __restrict__ out) {
    int tid = blockIdx.x * 256 + threadIdx.x;
    if (tid >= MAX_BOXES * DET_DIM) return;
    int m = tid / DET_DIM;
    int e = tid - m * DET_DIM;
    uint32_t s = sel[m];
    out[tid] = (s == 0xFFFFFFFFu) ? 0.0f : det[(size_t)s * DET_DIM + e];
}

extern "C" void kernel_launch(void* const* d_in, const int* in_sizes, int n_in,
                              void* d_out, int out_size, void* d_ws, size_t ws_size,
                              hipStream_t stream) {
    const float* boxes = (const float*)d_in[0];
    const float* cls   = (const float*)d_in[1];
    const float* det   = (const float*)d_in[2];
    float* out = (float*)d_out;
    char* ws = (char*)d_ws;

    uint32_t* keys = (uint32_t*)(ws + OFF_KEYS);
    uint32_t* h1   = (uint32_t*)(ws + OFF_HIST1);
    uint32_t* h2   = (uint32_t*)(ws + OFF_HIST2);
    uint32_t* st   = (uint32_t*)(ws + OFF_STATE);
    uint32_t* list = (uint32_t*)(ws + OFF_LIST);
    uint32_t* topk = (uint32_t*)(ws + OFF_TOPK);
    float4*   boxk = (float4*)(ws + OFF_BOXK);
    unsigned long long* mask = (unsigned long long*)(ws + OFF_MASK);
    uint32_t* sel  = (uint32_t*)(ws + OFF_SEL);

    k_init<<<dim3((ZERO_WORDS + 1023) / 1024), dim3(1024), 0, stream>>>(h1);
    k_scores<<<dim3(N_ANCH / 256), dim3(256), 0, stream>>>(cls, keys, h1);
    k_pass2<<<dim3(256), dim3(256), 0, stream>>>(keys, h1, h2, st);
    k_pass3c<<<dim3(256), dim3(256), 0, stream>>>(keys, h2, st, list);
    k_sort<<<dim3(1), dim3(1024), 0, stream>>>(keys, st, list, topk,
                                               (const float4*)boxes, boxk);
    k_mask<<<dim3(256), dim3(256), 0, stream>>>(boxk, mask);
    k_nms<<<dim3(1), dim3(256), 0, stream>>>(mask, topk, sel);
    k_out<<<dim3((MAX_BOXES * DET_DIM + 255) / 256), dim3(256), 0, stream>>>(sel, det, out);
}